// Round 1
// baseline (225.992 us; speedup 1.0000x reference)
//
#include <hip/hip_runtime.h>
#include <math.h>

#define BB 8
#define LL 1024
#define HH 8
#define DD 64
#define SS 35
#define UU 35
#define BH (BB*HH)
#define GRP 5            // query-rows per attn block
#define NGRP (UU/GRP)    // 7

__device__ __forceinline__ size_t qkv_off(int b, int l, int h, int d) {
    return (((size_t)b*LL + l)*HH + h)*DD + d;
}

// ---------------- Stage 1: sparsity measurement M ----------------
// one thread per (b,h,q)
__global__ __launch_bounds__(256) void kernel_M(const float* __restrict__ Q,
                                                const float* __restrict__ K,
                                                const int*   __restrict__ sidx,
                                                float* __restrict__ M) {
    int t  = blockIdx.x * 256 + threadIdx.x;   // B*H*L threads
    int q  = t & (LL - 1);
    int bh = t >> 10;
    int b  = bh >> 3, h = bh & 7;

    const float4* qr = reinterpret_cast<const float4*>(Q + qkv_off(b, q, h, 0));
    float4 qreg[16];
#pragma unroll
    for (int i = 0; i < 16; i++) qreg[i] = qr[i];

    const int* si = sidx + q * SS;
    float mx = -INFINITY, sm = 0.f;
    for (int s = 0; s < SS; s++) {
        int idx = si[s];
        const float4* kr = reinterpret_cast<const float4*>(K + qkv_off(b, idx, h, 0));
        float dot = 0.f;
#pragma unroll
        for (int i = 0; i < 16; i++) {
            float4 k4 = kr[i];
            dot += qreg[i].x * k4.x + qreg[i].y * k4.y
                 + qreg[i].z * k4.z + qreg[i].w * k4.w;
        }
        mx = fmaxf(mx, dot);
        sm += dot;
    }
    M[bh * LL + q] = mx - sm * (1.0f / LL);
}

// ---------------- Stage 2: top-U per (b,h) ----------------
__global__ __launch_bounds__(256) void kernel_topk(const float* __restrict__ M,
                                                   int* __restrict__ top) {
    __shared__ float vals[LL];
    __shared__ float rv[256];
    __shared__ int   ri[256];
    int bh  = blockIdx.x;
    int tid = threadIdx.x;
    for (int i = tid; i < LL; i += 256) vals[i] = M[bh * LL + i];
    __syncthreads();
    for (int k = 0; k < UU; k++) {
        float bv = -INFINITY; int bi = 0;
        for (int i = tid; i < LL; i += 256) {
            float v = vals[i];
            if (v > bv) { bv = v; bi = i; }   // ties keep lower index
        }
        rv[tid] = bv; ri[tid] = bi;
        __syncthreads();
        for (int s = 128; s > 0; s >>= 1) {
            if (tid < s) {
                float ov = rv[tid + s]; int oi = ri[tid + s];
                if (ov > rv[tid] || (ov == rv[tid] && oi < ri[tid])) {
                    rv[tid] = ov; ri[tid] = oi;
                }
            }
            __syncthreads();
        }
        if (tid == 0) { top[bh * UU + k] = ri[0]; vals[ri[0]] = -INFINITY; }
        __syncthreads();
    }
}

// ---------------- Stage 3: context = cumsum(V)/denom ----------------
// one block per (b,h); 16 chunks x 64 d-lanes
__global__ __launch_bounds__(1024) void kernel_cumsum(const float* __restrict__ V,
                                                      float* __restrict__ out) {
    __shared__ float csum[16 * 64];
    int bh = blockIdx.x;
    int b  = bh >> 3, h = bh & 7;
    int tid = threadIdx.x;
    int d = tid & 63, c = tid >> 6;
    int l0 = c * 64;
    const float* vp = V + qkv_off(b, l0, h, d);
    float s = 0.f;
    for (int i = 0; i < 64; i++) s += vp[(size_t)i * (HH * DD)];
    csum[c * 64 + d] = s;
    __syncthreads();
    float prefix = 0.f;
    for (int cc = 0; cc < c; cc++) prefix += csum[cc * 64 + d];
    float run = prefix;
    float* op = out + qkv_off(b, l0, h, d);
    for (int i = 0; i < 64; i++) {
        run += vp[(size_t)i * (HH * DD)];
        op[(size_t)i * (HH * DD)] = run / (float)(l0 + i + 1);
    }
}

// ---------------- Stage 4: attention on selected queries ----------------
// one block per (b,h, group-of-5-rows)
__global__ __launch_bounds__(256) void kernel_attn(const float* __restrict__ Q,
                                                   const float* __restrict__ K,
                                                   const float* __restrict__ V,
                                                   const int*   __restrict__ top,
                                                   float* __restrict__ out) {
    __shared__ float4 q_lds4[GRP][16];
    __shared__ float  scores[GRP][LL];
    __shared__ float  red[256];
    __shared__ float  denr[GRP];
    __shared__ int    qpos[GRP];
    __shared__ float  pv[4][GRP][64];

    int blk = blockIdx.x;          // bh*NGRP + g
    int bh  = blk / NGRP;
    int g   = blk % NGRP;
    int b   = bh >> 3, h = bh & 7;
    int tid = threadIdx.x;
    int r0  = g * GRP;

    if (tid < GRP) qpos[tid] = top[bh * UU + r0 + tid];
    __syncthreads();
    for (int i = tid; i < GRP * DD; i += 256) {
        int r = i / DD, d = i % DD;
        ((float*)q_lds4)[i] = Q[qkv_off(b, qpos[r], h, d)];
    }
    __syncthreads();

    const float scale = 0.125f;  // 1/sqrt(64)

    // scores[r][l] = scale * (Q_r . K_l)
    for (int li = 0; li < 4; li++) {
        int l = li * 256 + tid;
        const float4* kr = reinterpret_cast<const float4*>(K + qkv_off(b, l, h, 0));
        float dot[GRP];
#pragma unroll
        for (int r = 0; r < GRP; r++) dot[r] = 0.f;
#pragma unroll
        for (int i = 0; i < 16; i++) {
            float4 k4 = kr[i];
#pragma unroll
            for (int r = 0; r < GRP; r++) {
                float4 qq = q_lds4[r][i];
                dot[r] += qq.x * k4.x + qq.y * k4.y + qq.z * k4.z + qq.w * k4.w;
            }
        }
#pragma unroll
        for (int r = 0; r < GRP; r++) scores[r][l] = dot[r] * scale;
    }
    __syncthreads();

    // softmax per row
    for (int r = 0; r < GRP; r++) {
        float lm = -INFINITY;
        for (int li = 0; li < 4; li++) lm = fmaxf(lm, scores[r][li * 256 + tid]);
        red[tid] = lm;
        __syncthreads();
        for (int s = 128; s > 0; s >>= 1) {
            if (tid < s) red[tid] = fmaxf(red[tid], red[tid + s]);
            __syncthreads();
        }
        float m = red[0];
        __syncthreads();
        float ls = 0.f;
        for (int li = 0; li < 4; li++) {
            int l = li * 256 + tid;
            float e = expf(scores[r][l] - m);
            scores[r][l] = e;
            ls += e;
        }
        red[tid] = ls;
        __syncthreads();
        for (int s = 128; s > 0; s >>= 1) {
            if (tid < s) red[tid] += red[tid + s];
            __syncthreads();
        }
        if (tid == 0) denr[r] = red[0];
        __syncthreads();
    }

    // PV: update[r][d] = sum_l p[r][l] * V[l][d]
    int d = tid & 63, w = tid >> 6;
    float acc[GRP];
#pragma unroll
    for (int r = 0; r < GRP; r++) acc[r] = 0.f;
    for (int l = w * 256; l < w * 256 + 256; l++) {
        float v = V[qkv_off(b, l, h, d)];
#pragma unroll
        for (int r = 0; r < GRP; r++) acc[r] += scores[r][l] * v;
    }
#pragma unroll
    for (int r = 0; r < GRP; r++) pv[w][r][d] = acc[r];
    __syncthreads();

    if (tid < DD) {
        for (int r = 0; r < GRP; r++) {
            float o = (pv[0][r][tid] + pv[1][r][tid] + pv[2][r][tid] + pv[3][r][tid]) / denr[r];
            out[qkv_off(b, qpos[r], h, tid)] = o;
        }
    }
}

extern "C" void kernel_launch(void* const* d_in, const int* in_sizes, int n_in,
                              void* d_out, int out_size, void* d_ws, size_t ws_size,
                              hipStream_t stream) {
    const float* Q    = (const float*)d_in[0];
    const float* K    = (const float*)d_in[1];
    const float* V    = (const float*)d_in[2];
    const int*   sidx = (const int*)d_in[3];
    float* out = (float*)d_out;

    float* M   = (float*)d_ws;
    int*   top = (int*)((char*)d_ws + (size_t)BH * LL * sizeof(float));

    kernel_M     <<<BH * LL / 256, 256, 0, stream>>>(Q, K, sidx, M);
    kernel_topk  <<<BH, 256, 0, stream>>>(M, top);
    kernel_cumsum<<<BH, 1024, 0, stream>>>(V, out);
    kernel_attn  <<<BH * NGRP, 256, 0, stream>>>(Q, K, V, top, out);
}

// Round 2
// 138.543 us; speedup vs baseline: 1.6312x; 1.6312x over previous
//
#include <hip/hip_runtime.h>
#include <math.h>

#define BB 8
#define LL 1024
#define HH 8
#define DD 64
#define SS 35
#define UU 35
#define BH (BB*HH)
#define GRP 5            // query-rows per attn block
#define NGRP (UU/GRP)    // 7
#define CH 32            // cumsum chunks per (b,h)
#define CROWS (LL/CH)    // 32 rows per chunk

__device__ __forceinline__ size_t qkv_off(int b, int l, int h, int d) {
    return (((size_t)b*LL + l)*HH + h)*DD + d;
}

// ---------------- Stage 1: sparsity measurement M ----------------
// one WAVE per (b,h,q); 16-lane groups cooperatively read K rows (coalesced)
__global__ __launch_bounds__(256) void kernel_M(const float* __restrict__ Q,
                                                const float* __restrict__ K,
                                                const int*   __restrict__ sidx,
                                                float* __restrict__ M) {
    int wave = blockIdx.x * 4 + (threadIdx.x >> 6);   // 0 .. BH*LL-1
    int lane = threadIdx.x & 63;
    int q  = wave & (LL - 1);
    int bh = wave >> 10;
    int b  = bh >> 3, h = bh & 7;
    int sub = lane & 15, grp = lane >> 4;

    const float4 q4 = *reinterpret_cast<const float4*>(Q + qkv_off(b, q, h, sub * 4));
    const int* si = sidx + q * SS;

    float mx = -INFINITY, sm = 0.f;
    for (int s0 = 0; s0 < SS; s0 += 4) {
        int s = s0 + grp;
        bool valid = (s < SS);
        int idx = si[valid ? s : 0];
        float4 k4 = *reinterpret_cast<const float4*>(K + qkv_off(b, idx, h, sub * 4));
        float p = q4.x * k4.x + q4.y * k4.y + q4.z * k4.z + q4.w * k4.w;
        p += __shfl_xor(p, 1);
        p += __shfl_xor(p, 2);
        p += __shfl_xor(p, 4);
        p += __shfl_xor(p, 8);
        if (valid) { mx = fmaxf(mx, p); sm += p; }
    }
    mx = fmaxf(mx, __shfl_xor(mx, 16)); sm += __shfl_xor(sm, 16);
    mx = fmaxf(mx, __shfl_xor(mx, 32)); sm += __shfl_xor(sm, 32);
    if (lane == 0) M[bh * LL + q] = mx - sm * (1.0f / LL);
}

// ---------------- Stage 2: top-U per (b,h), single wave, shfl-only ----------------
__global__ __launch_bounds__(64) void kernel_topk(const float* __restrict__ M,
                                                  int* __restrict__ top) {
    int bh = blockIdx.x, lane = threadIdx.x;
    float v[16];
#pragma unroll
    for (int i = 0; i < 16; i++) v[i] = M[bh * LL + i * 64 + lane];

    for (int k = 0; k < UU; k++) {
        float bv = -INFINITY; int bi = 0x7fffffff;
#pragma unroll
        for (int i = 0; i < 16; i++) {
            if (v[i] > bv) { bv = v[i]; bi = i * 64 + lane; }   // ascending i -> lowest idx on tie
        }
#pragma unroll
        for (int w = 1; w < 64; w <<= 1) {
            float ov = __shfl_xor(bv, w);
            int   oi = __shfl_xor(bi, w);
            if (ov > bv || (ov == bv && oi < bi)) { bv = ov; bi = oi; }
        }
        if (lane == 0) top[bh * UU + k] = bi;
        if ((bi & 63) == lane) {
            int slot = bi >> 6;
#pragma unroll
            for (int i = 0; i < 16; i++) if (i == slot) v[i] = -INFINITY;  // static idx, no scratch
        }
    }
}

// ---------------- Stage 3a: per-chunk column sums ----------------
__global__ __launch_bounds__(256) void kernel_csum1(const float* __restrict__ V,
                                                    float* __restrict__ csum) {
    int blk = blockIdx.x;            // bh*CH + c
    int bh = blk >> 5, c = blk & (CH - 1);
    int b = bh >> 3, h = bh & 7;
    int d = threadIdx.x & 63, seg = threadIdx.x >> 6;
    int l0 = c * CROWS + seg * (CROWS / 4);
    const float* vp = V + qkv_off(b, l0, h, d);
    float s = 0.f;
#pragma unroll
    for (int i = 0; i < CROWS / 4; i++) s += vp[(size_t)i * (HH * DD)];
    __shared__ float red[4][64];
    red[seg][d] = s;
    __syncthreads();
    if (seg == 0)
        csum[(size_t)blk * 64 + d] = red[0][d] + red[1][d] + red[2][d] + red[3][d];
}

// ---------------- Stage 3b: scan within chunk, write context ----------------
__global__ __launch_bounds__(64) void kernel_csum2(const float* __restrict__ V,
                                                   const float* __restrict__ csum,
                                                   float* __restrict__ out) {
    int blk = blockIdx.x;
    int bh = blk >> 5, c = blk & (CH - 1);
    int b = bh >> 3, h = bh & 7;
    int d = threadIdx.x;
    float prefix = 0.f;
    for (int cc = 0; cc < c; cc++) prefix += csum[(size_t)(bh * CH + cc) * 64 + d];
    int l0 = c * CROWS;
    const float* vp = V + qkv_off(b, l0, h, d);
    float* op = out + qkv_off(b, l0, h, d);
    float run = prefix;
#pragma unroll
    for (int i = 0; i < CROWS; i++) {
        run += vp[(size_t)i * (HH * DD)];
        op[(size_t)i * (HH * DD)] = run / (float)(l0 + i + 1);
    }
}

// ---------------- Stage 4: attention on selected queries ----------------
__global__ __launch_bounds__(256) void kernel_attn(const float* __restrict__ Q,
                                                   const float* __restrict__ K,
                                                   const float* __restrict__ V,
                                                   const int*   __restrict__ top,
                                                   float* __restrict__ out) {
    __shared__ float4 q_lds4[GRP][16];
    __shared__ float  scores[GRP][LL];
    __shared__ float  denr[GRP];
    __shared__ int    qpos[GRP];
    __shared__ float  pv[4][GRP][64];

    int blk = blockIdx.x;          // bh*NGRP + g
    int bh  = blk / NGRP;
    int g   = blk % NGRP;
    int b   = bh >> 3, h = bh & 7;
    int tid = threadIdx.x;
    int r0  = g * GRP;

    if (tid < GRP) qpos[tid] = top[bh * UU + r0 + tid];
    __syncthreads();
    for (int i = tid; i < GRP * DD; i += 256) {
        int r = i / DD, d = i % DD;
        ((float*)q_lds4)[i] = Q[qkv_off(b, qpos[r], h, d)];
    }
    __syncthreads();

    const float scale = 0.125f;  // 1/sqrt(64)

    // scores[r][l] = scale * (Q_r . K_l)
    for (int li = 0; li < 4; li++) {
        int l = li * 256 + tid;
        const float4* kr = reinterpret_cast<const float4*>(K + qkv_off(b, l, h, 0));
        float dot[GRP];
#pragma unroll
        for (int r = 0; r < GRP; r++) dot[r] = 0.f;
#pragma unroll
        for (int i = 0; i < 16; i++) {
            float4 k4 = kr[i];
#pragma unroll
            for (int r = 0; r < GRP; r++) {
                float4 qq = q_lds4[r][i];
                dot[r] += qq.x * k4.x + qq.y * k4.y + qq.z * k4.z + qq.w * k4.w;
            }
        }
#pragma unroll
        for (int r = 0; r < GRP; r++) scores[r][l] = dot[r] * scale;
    }
    __syncthreads();

    // softmax: one wave per row, shfl-only reductions
    {
        int w = tid >> 6, lane = tid & 63;
        for (int r = w; r < GRP; r += 4) {
            float lv[16];
            float lm = -INFINITY;
#pragma unroll
            for (int i = 0; i < 16; i++) {
                lv[i] = scores[r][i * 64 + lane];
                lm = fmaxf(lm, lv[i]);
            }
#pragma unroll
            for (int x = 1; x < 64; x <<= 1) lm = fmaxf(lm, __shfl_xor(lm, x));
            float ls = 0.f;
#pragma unroll
            for (int i = 0; i < 16; i++) {
                float e = __expf(lv[i] - lm);
                scores[r][i * 64 + lane] = e;
                ls += e;
            }
#pragma unroll
            for (int x = 1; x < 64; x <<= 1) ls += __shfl_xor(ls, x);
            if (lane == 0) denr[r] = ls;
        }
    }
    __syncthreads();

    // PV: update[r][d] = sum_l p[r][l] * V[l][d]
    int d = tid & 63, w = tid >> 6;
    float acc[GRP];
#pragma unroll
    for (int r = 0; r < GRP; r++) acc[r] = 0.f;
    for (int l = w * 256; l < w * 256 + 256; l++) {
        float v = V[qkv_off(b, l, h, d)];
#pragma unroll
        for (int r = 0; r < GRP; r++) acc[r] += scores[r][l] * v;
    }
#pragma unroll
    for (int r = 0; r < GRP; r++) pv[w][r][d] = acc[r];
    __syncthreads();

    if (tid < DD) {
        for (int r = 0; r < GRP; r++) {
            float o = (pv[0][r][tid] + pv[1][r][tid] + pv[2][r][tid] + pv[3][r][tid]) / denr[r];
            out[qkv_off(b, qpos[r], h, tid)] = o;
        }
    }
}

extern "C" void kernel_launch(void* const* d_in, const int* in_sizes, int n_in,
                              void* d_out, int out_size, void* d_ws, size_t ws_size,
                              hipStream_t stream) {
    const float* Q    = (const float*)d_in[0];
    const float* K    = (const float*)d_in[1];
    const float* V    = (const float*)d_in[2];
    const int*   sidx = (const int*)d_in[3];
    float* out = (float*)d_out;

    float* M    = (float*)d_ws;
    int*   top  = (int*)((char*)d_ws + (size_t)BH * LL * sizeof(float));
    float* csum = (float*)((char*)d_ws + (size_t)BH * LL * sizeof(float)
                                       + (size_t)BH * UU * sizeof(int));

    kernel_M    <<<BH * LL / 4, 256, 0, stream>>>(Q, K, sidx, M);
    kernel_topk <<<BH, 64, 0, stream>>>(M, top);
    kernel_csum1<<<BH * CH, 256, 0, stream>>>(V, csum);
    kernel_csum2<<<BH * CH, 64, 0, stream>>>(V, csum, out);
    kernel_attn <<<BH * NGRP, 256, 0, stream>>>(Q, K, V, top, out);
}

// Round 3
// 99.466 us; speedup vs baseline: 2.2720x; 1.3929x over previous
//
#include <hip/hip_runtime.h>
#include <math.h>

#define BB 8
#define LL 1024
#define HH 8
#define DD 64
#define SS 35
#define UU 35
#define BH (BB*HH)
#define CH 32            // cumsum chunks per (b,h)
#define CROWS (LL/CH)    // 32 rows per chunk
#define NCHK 4           // attention K/V chunks
#define CHK 256          // keys per chunk
#define RPAD 48          // padded row count (35 -> 48, 3 m-tiles)

typedef __attribute__((ext_vector_type(8))) short short8;
typedef __attribute__((ext_vector_type(4))) float f32x4;

__device__ __forceinline__ size_t qkv_off(int b, int l, int h, int d) {
    return (((size_t)b*LL + l)*HH + h)*DD + d;
}

__device__ __forceinline__ unsigned short f2bf(float x) {
    unsigned int u = __float_as_uint(x);
    u = (u + 0x7fffu + ((u >> 16) & 1u)) >> 16;
    return (unsigned short)u;
}

__device__ __forceinline__ short8 ld_bf8_g(const float* __restrict__ p) {
    float4 x = *reinterpret_cast<const float4*>(p);
    float4 y = *reinterpret_cast<const float4*>(p + 4);
    short8 r;
    r[0] = (short)f2bf(x.x); r[1] = (short)f2bf(x.y);
    r[2] = (short)f2bf(x.z); r[3] = (short)f2bf(x.w);
    r[4] = (short)f2bf(y.x); r[5] = (short)f2bf(y.y);
    r[6] = (short)f2bf(y.z); r[7] = (short)f2bf(y.w);
    return r;
}

// ---------------- Stage 1: sparsity measurement M ----------------
__global__ __launch_bounds__(256) void kernel_M(const float* __restrict__ Q,
                                                const float* __restrict__ K,
                                                const int*   __restrict__ sidx,
                                                float* __restrict__ M) {
    int wave = blockIdx.x * 4 + (threadIdx.x >> 6);
    int lane = threadIdx.x & 63;
    int q  = wave & (LL - 1);
    int bh = wave >> 10;
    int b  = bh >> 3, h = bh & 7;
    int sub = lane & 15, grp = lane >> 4;

    const float4 q4 = *reinterpret_cast<const float4*>(Q + qkv_off(b, q, h, sub * 4));
    const int* si = sidx + q * SS;

    float mx = -INFINITY, sm = 0.f;
    for (int s0 = 0; s0 < SS; s0 += 4) {
        int s = s0 + grp;
        bool valid = (s < SS);
        int idx = si[valid ? s : 0];
        float4 k4 = *reinterpret_cast<const float4*>(K + qkv_off(b, idx, h, sub * 4));
        float p = q4.x * k4.x + q4.y * k4.y + q4.z * k4.z + q4.w * k4.w;
        p += __shfl_xor(p, 1);
        p += __shfl_xor(p, 2);
        p += __shfl_xor(p, 4);
        p += __shfl_xor(p, 8);
        if (valid) { mx = fmaxf(mx, p); sm += p; }
    }
    mx = fmaxf(mx, __shfl_xor(mx, 16)); sm += __shfl_xor(sm, 16);
    mx = fmaxf(mx, __shfl_xor(mx, 32)); sm += __shfl_xor(sm, 32);
    if (lane == 0) M[bh * LL + q] = mx - sm * (1.0f / LL);
}

// ---------------- Stage 2: top-U per (b,h), single wave, shfl-only ----------------
__global__ __launch_bounds__(64) void kernel_topk(const float* __restrict__ M,
                                                  int* __restrict__ top) {
    int bh = blockIdx.x, lane = threadIdx.x;
    float v[16];
#pragma unroll
    for (int i = 0; i < 16; i++) v[i] = M[bh * LL + i * 64 + lane];

    for (int k = 0; k < UU; k++) {
        float bv = -INFINITY; int bi = 0x7fffffff;
#pragma unroll
        for (int i = 0; i < 16; i++) {
            if (v[i] > bv) { bv = v[i]; bi = i * 64 + lane; }
        }
#pragma unroll
        for (int w = 1; w < 64; w <<= 1) {
            float ov = __shfl_xor(bv, w);
            int   oi = __shfl_xor(bi, w);
            if (ov > bv || (ov == bv && oi < bi)) { bv = ov; bi = oi; }
        }
        if (lane == 0) top[bh * UU + k] = bi;
        if ((bi & 63) == lane) {
            int slot = bi >> 6;
#pragma unroll
            for (int i = 0; i < 16; i++) if (i == slot) v[i] = -INFINITY;
        }
    }
}

// ---------------- Stage 3a: per-chunk column sums ----------------
__global__ __launch_bounds__(256) void kernel_csum1(const float* __restrict__ V,
                                                    float* __restrict__ csum) {
    int blk = blockIdx.x;
    int bh = blk >> 5, c = blk & (CH - 1);
    int b = bh >> 3, h = bh & 7;
    int d = threadIdx.x & 63, seg = threadIdx.x >> 6;
    int l0 = c * CROWS + seg * (CROWS / 4);
    const float* vp = V + qkv_off(b, l0, h, d);
    float s = 0.f;
#pragma unroll
    for (int i = 0; i < CROWS / 4; i++) s += vp[(size_t)i * (HH * DD)];
    __shared__ float red[4][64];
    red[seg][d] = s;
    __syncthreads();
    if (seg == 0)
        csum[(size_t)blk * 64 + d] = red[0][d] + red[1][d] + red[2][d] + red[3][d];
}

// ---------------- Stage 3b: scan within chunk, write context ----------------
__global__ __launch_bounds__(64) void kernel_csum2(const float* __restrict__ V,
                                                   const float* __restrict__ csum,
                                                   float* __restrict__ out) {
    int blk = blockIdx.x;
    int bh = blk >> 5, c = blk & (CH - 1);
    int b = bh >> 3, h = bh & 7;
    int d = threadIdx.x;
    float prefix = 0.f;
    for (int cc = 0; cc < c; cc++) prefix += csum[(size_t)(bh * CH + cc) * 64 + d];
    int l0 = c * CROWS;
    const float* vp = V + qkv_off(b, l0, h, d);
    float* op = out + qkv_off(b, l0, h, d);
    float run = prefix;
#pragma unroll
    for (int i = 0; i < CROWS; i++) {
        run += vp[(size_t)i * (HH * DD)];
        op[(size_t)i * (HH * DD)] = run / (float)(l0 + i + 1);
    }
}

// ---------------- Stage 4a: MFMA flash-attention partials per (bh, chunk) ----------------
// block = 256 threads (4 waves). Wave w owns score cols [w*64, w*64+64) and
// PV d-tile [w*16, w*16+16). Q/K fragments straight from global (L1), V^T in LDS.
__global__ __launch_bounds__(256) void kernel_attn_part(const float* __restrict__ Q,
                                                        const float* __restrict__ K,
                                                        const float* __restrict__ V,
                                                        const int*   __restrict__ top,
                                                        float* __restrict__ m_ws,
                                                        float* __restrict__ se_ws,
                                                        float* __restrict__ pv_ws) {
    __shared__ unsigned short vt[64 * CHK];      // V^T, 16B-slot swizzled: slot' = (l>>3) ^ (d&31)
    __shared__ unsigned short p_lds[RPAD * CHK]; // P (exp'd scores), bf16
    __shared__ float red_m[4][RPAD];
    __shared__ float red_se[4][RPAD];
    __shared__ int   qpos_s[RPAD];

    const int blk = blockIdx.x;          // bh*NCHK + ch
    const int bh  = blk >> 2;
    const int ch  = blk & 3;
    const int b   = bh >> 3, h = bh & 7;
    const int l0  = ch * CHK;
    const int tid = threadIdx.x;
    const int w    = tid >> 6;
    const int lane = tid & 63;
    const int c    = lane & 15;          // col-in-tile
    const int g    = lane >> 4;          // k-group / row-quad
    const float scale = 0.125f;

    if (tid < RPAD) qpos_s[tid] = top[bh * UU + (tid < UU ? tid : UU - 1)];

    // ---- stage V^T into LDS (bf16, packed 8-along-l per write) ----
#pragma unroll
    for (int i = 0; i < 8; i++) {
        int task = i * 256 + tid;        // 2048 tasks: (lq8 0..31) x (d 0..63)
        int d   = task & 63;
        int lq8 = task >> 6;
        float vv[8];
#pragma unroll
        for (int j = 0; j < 8; j++)
            vv[j] = V[qkv_off(b, l0 + lq8 * 8 + j, h, d)];
        short8 pk;
#pragma unroll
        for (int j = 0; j < 8; j++) pk[j] = (short)f2bf(vv[j]);
        *reinterpret_cast<short8*>(vt + d * CHK + (((lq8 ^ (d & 31)) << 3))) = pk;
    }
    __syncthreads();

    // ---- score GEMM: S(48 x 256) = Q(48x64) . K^T ; wave w -> cols w*64.. ----
    f32x4 acc[3][4];
#pragma unroll
    for (int mt = 0; mt < 3; mt++)
#pragma unroll
        for (int nt = 0; nt < 4; nt++) acc[mt][nt] = (f32x4){0.f, 0.f, 0.f, 0.f};

#pragma unroll
    for (int ks = 0; ks < 2; ks++) {
        int k0 = ks * 32 + g * 8;
        short8 af[3];
#pragma unroll
        for (int mt = 0; mt < 3; mt++) {
            int row = mt * 16 + c;
            af[mt] = ld_bf8_g(Q + qkv_off(b, qpos_s[row], h, k0));
        }
#pragma unroll
        for (int nt = 0; nt < 4; nt++) {
            int kl = l0 + w * 64 + nt * 16 + c;
            short8 bf = ld_bf8_g(K + qkv_off(b, kl, h, k0));
#pragma unroll
            for (int mt = 0; mt < 3; mt++)
                acc[mt][nt] = __builtin_amdgcn_mfma_f32_16x16x32_bf16(af[mt], bf, acc[mt][nt], 0, 0, 0);
        }
    }

    // ---- wave-local row max (over 4 nt and 16 lanes of col-group) ----
    float tmax[3][4];
#pragma unroll
    for (int mt = 0; mt < 3; mt++)
#pragma unroll
        for (int r = 0; r < 4; r++) {
            float m = fmaxf(fmaxf(acc[mt][0][r], acc[mt][1][r]),
                            fmaxf(acc[mt][2][r], acc[mt][3][r]));
            m = fmaxf(m, __shfl_xor(m, 1));
            m = fmaxf(m, __shfl_xor(m, 2));
            m = fmaxf(m, __shfl_xor(m, 4));
            m = fmaxf(m, __shfl_xor(m, 8));
            tmax[mt][r] = m;
        }
    if (c == 0) {
#pragma unroll
        for (int mt = 0; mt < 3; mt++)
#pragma unroll
            for (int r = 0; r < 4; r++)
                red_m[w][mt * 16 + g * 4 + r] = tmax[mt][r];
    }
    __syncthreads();

    // ---- chunk row max, exp, row sums, write P ----
    float tse[3][4];
#pragma unroll
    for (int mt = 0; mt < 3; mt++)
#pragma unroll
        for (int r = 0; r < 4; r++) {
            int row = mt * 16 + g * 4 + r;
            float m = fmaxf(fmaxf(red_m[0][row], red_m[1][row]),
                            fmaxf(red_m[2][row], red_m[3][row]));
            float s = 0.f;
#pragma unroll
            for (int nt = 0; nt < 4; nt++) {
                float p = __expf(scale * (acc[mt][nt][r] - m));
                acc[mt][nt][r] = p;
                s += p;
                p_lds[row * CHK + w * 64 + nt * 16 + c] = f2bf(p);
            }
            s += __shfl_xor(s, 1);
            s += __shfl_xor(s, 2);
            s += __shfl_xor(s, 4);
            s += __shfl_xor(s, 8);
            tse[mt][r] = s;
        }
    if (c == 0) {
#pragma unroll
        for (int mt = 0; mt < 3; mt++)
#pragma unroll
            for (int r = 0; r < 4; r++)
                red_se[w][mt * 16 + g * 4 + r] = tse[mt][r];
    }
    __syncthreads();

    // ---- chunk stats to workspace ----
    if (tid < RPAD) {
        float mm = fmaxf(fmaxf(red_m[0][tid], red_m[1][tid]),
                         fmaxf(red_m[2][tid], red_m[3][tid]));
        float ss = red_se[0][tid] + red_se[1][tid] + red_se[2][tid] + red_se[3][tid];
        m_ws[blk * RPAD + tid]  = mm;
        se_ws[blk * RPAD + tid] = ss;
    }

    // ---- PV GEMM: pv(48 x 64) = P(48x256) . V(256x64); wave w -> d-tile w ----
    f32x4 acc2[3];
#pragma unroll
    for (int mt = 0; mt < 3; mt++) acc2[mt] = (f32x4){0.f, 0.f, 0.f, 0.f};

#pragma unroll
    for (int ks = 0; ks < 8; ks++) {
        int slot = ks * 4 + g;           // logical l-octet index 0..31
        int d    = w * 16 + c;
        short8 bf = *reinterpret_cast<const short8*>(
            vt + d * CHK + ((slot ^ (d & 31)) << 3));
#pragma unroll
        for (int mt = 0; mt < 3; mt++) {
            short8 af = *reinterpret_cast<const short8*>(
                p_lds + (mt * 16 + c) * CHK + ks * 32 + g * 8);
            acc2[mt] = __builtin_amdgcn_mfma_f32_16x16x32_bf16(af, bf, acc2[mt], 0, 0, 0);
        }
    }

#pragma unroll
    for (int mt = 0; mt < 3; mt++)
#pragma unroll
        for (int r = 0; r < 4; r++) {
            int row = mt * 16 + g * 4 + r;
            pv_ws[((size_t)blk * RPAD + row) * 64 + w * 16 + c] = acc2[mt][r];
        }
}

// ---------------- Stage 4b: combine chunk partials, write selected rows ----------------
__global__ __launch_bounds__(256) void kernel_attn_comb(const int* __restrict__ top,
                                                        const float* __restrict__ m_ws,
                                                        const float* __restrict__ se_ws,
                                                        const float* __restrict__ pv_ws,
                                                        float* __restrict__ out) {
    int bh = blockIdx.x;
    int b = bh >> 3, h = bh & 7;
    const float scale = 0.125f;
    for (int idx = threadIdx.x; idx < UU * 64; idx += 256) {
        int r = idx >> 6, d = idx & 63;
        float mc[NCHK];
        float mm = -INFINITY;
#pragma unroll
        for (int ch = 0; ch < NCHK; ch++) {
            mc[ch] = m_ws[(bh * NCHK + ch) * RPAD + r];
            mm = fmaxf(mm, mc[ch]);
        }
        float num = 0.f, den = 0.f;
#pragma unroll
        for (int ch = 0; ch < NCHK; ch++) {
            float f = __expf(scale * (mc[ch] - mm));
            num += f * pv_ws[((size_t)(bh * NCHK + ch) * RPAD + r) * 64 + d];
            den += f * se_ws[(bh * NCHK + ch) * RPAD + r];
        }
        out[qkv_off(b, top[bh * UU + r], h, d)] = num / den;
    }
}

extern "C" void kernel_launch(void* const* d_in, const int* in_sizes, int n_in,
                              void* d_out, int out_size, void* d_ws, size_t ws_size,
                              hipStream_t stream) {
    const float* Q    = (const float*)d_in[0];
    const float* K    = (const float*)d_in[1];
    const float* V    = (const float*)d_in[2];
    const int*   sidx = (const int*)d_in[3];
    float* out = (float*)d_out;

    char* ws = (char*)d_ws;
    float* M     = (float*)(ws);                          // 256 KiB
    int*   top   = (int*)  (ws + 262144);                 // 9 KiB
    float* csum  = (float*)(ws + 271360);                 // 512 KiB
    float* m_ws  = (float*)(ws + 795648);                 // 48 KiB
    float* se_ws = (float*)(ws + 844800);                 // 48 KiB
    float* pv_ws = (float*)(ws + 893952);                 // 3 MiB

    kernel_M        <<<BH * LL / 4, 256, 0, stream>>>(Q, K, sidx, M);
    kernel_topk     <<<BH, 64, 0, stream>>>(M, top);
    kernel_csum1    <<<BH * CH, 256, 0, stream>>>(V, csum);
    kernel_csum2    <<<BH * CH, 64, 0, stream>>>(V, csum, out);
    kernel_attn_part<<<BH * NCHK, 256, 0, stream>>>(Q, K, V, top, m_ws, se_ws, pv_ws);
    kernel_attn_comb<<<BH, 256, 0, stream>>>(top, m_ws, se_ws, pv_ws, out);
}

// Round 4
// 83.569 us; speedup vs baseline: 2.7042x; 1.1902x over previous
//
#include <hip/hip_runtime.h>
#include <math.h>

#define BB 8
#define LL 1024
#define HH 8
#define DD 64
#define SS 35
#define UU 35
#define BH (BB*HH)
#define CH 32            // cumsum chunks per (b,h)
#define CROWS (LL/CH)    // 32 rows per chunk
#define NCHK 4           // attention K/V chunks
#define CHK 256          // keys per chunk
#define RPAD 48          // padded row count (35 -> 48, 3 m-tiles)

#define MBLOCKS 16384    // kernel_M waves/4
#define C1BLOCKS (BH*CH) // 2048

typedef __attribute__((ext_vector_type(8))) short short8;
typedef __attribute__((ext_vector_type(4))) float f32x4;

__device__ __forceinline__ size_t qkv_off(int b, int l, int h, int d) {
    return (((size_t)b*LL + l)*HH + h)*DD + d;
}

__device__ __forceinline__ unsigned short f2bf(float x) {
    unsigned int u = __float_as_uint(x);
    u = (u + 0x7fffu + ((u >> 16) & 1u)) >> 16;
    return (unsigned short)u;
}

__device__ __forceinline__ short8 ld_bf8_g(const float* __restrict__ p) {
    float4 x = *reinterpret_cast<const float4*>(p);
    float4 y = *reinterpret_cast<const float4*>(p + 4);
    short8 r;
    r[0] = (short)f2bf(x.x); r[1] = (short)f2bf(x.y);
    r[2] = (short)f2bf(x.z); r[3] = (short)f2bf(x.w);
    r[4] = (short)f2bf(y.x); r[5] = (short)f2bf(y.y);
    r[6] = (short)f2bf(y.z); r[7] = (short)f2bf(y.w);
    return r;
}

// ---------------- L1: kernel_M (XCD-swizzled, unrolled) + csum1 fused ----------------
__global__ __launch_bounds__(256) void kernel_M_csum1(const float* __restrict__ Q,
                                                      const float* __restrict__ K,
                                                      const float* __restrict__ V,
                                                      const int*   __restrict__ sidx,
                                                      float* __restrict__ M,
                                                      float* __restrict__ csum) {
    int blk = blockIdx.x;
    if (blk < MBLOCKS) {
        // ---- sparsity measurement M: one wave per q ----
        // XCD swizzle: blk = (slot<<3)|xcd ; bh = ((slot>>8)<<3)|xcd -> bh%8==xcd
        int xcd  = blk & 7;
        int slot = blk >> 3;
        int bh   = ((slot >> 8) << 3) | xcd;
        int j    = slot & 255;
        int widx = threadIdx.x >> 6, lane = threadIdx.x & 63;
        int q = j * 4 + widx;
        int b = bh >> 3, h = bh & 7;
        int sub = lane & 15, grp = lane >> 4;

        const float4 q4 = *reinterpret_cast<const float4*>(Q + qkv_off(b, q, h, sub * 4));
        const int* si = sidx + q * SS;

        int idxv[9];
#pragma unroll
        for (int i = 0; i < 9; i++) {
            int s = i * 4 + grp;
            idxv[i] = si[s < SS ? s : 0];
        }
        float4 kv[9];
#pragma unroll
        for (int i = 0; i < 9; i++)
            kv[i] = *reinterpret_cast<const float4*>(K + qkv_off(b, idxv[i], h, sub * 4));

        float mx = -INFINITY, sm = 0.f;
#pragma unroll
        for (int i = 0; i < 9; i++) {
            float p = q4.x * kv[i].x + q4.y * kv[i].y + q4.z * kv[i].z + q4.w * kv[i].w;
            p += __shfl_xor(p, 1);
            p += __shfl_xor(p, 2);
            p += __shfl_xor(p, 4);
            p += __shfl_xor(p, 8);
            if (i * 4 + grp < SS) { mx = fmaxf(mx, p); sm += p; }
        }
        mx = fmaxf(mx, __shfl_xor(mx, 16)); sm += __shfl_xor(sm, 16);
        mx = fmaxf(mx, __shfl_xor(mx, 32)); sm += __shfl_xor(sm, 32);
        if (lane == 0) M[bh * LL + q] = mx - sm * (1.0f / LL);
    } else {
        // ---- csum1: per-chunk column sums ----
        int blk2 = blk - MBLOCKS;
        int bh = blk2 >> 5, c = blk2 & (CH - 1);
        int b = bh >> 3, h = bh & 7;
        int d = threadIdx.x & 63, seg = threadIdx.x >> 6;
        int l0 = c * CROWS + seg * (CROWS / 4);
        const float* vp = V + qkv_off(b, l0, h, d);
        float s = 0.f;
#pragma unroll
        for (int i = 0; i < CROWS / 4; i++) s += vp[(size_t)i * (HH * DD)];
        __shared__ float red[4][64];
        red[seg][d] = s;
        __syncthreads();
        if (seg == 0)
            csum[(size_t)blk2 * 64 + d] = red[0][d] + red[1][d] + red[2][d] + red[3][d];
    }
}

// ---------------- L2: topk + csum2 fused (64-thread blocks) ----------------
__global__ __launch_bounds__(64) void kernel_topk_csum2(const float* __restrict__ M,
                                                        int* __restrict__ top,
                                                        const float* __restrict__ V,
                                                        const float* __restrict__ csum,
                                                        float* __restrict__ out) {
    if (blockIdx.x < BH) {
        // ---- top-U per (b,h), single wave, shfl-only ----
        int bh = blockIdx.x, lane = threadIdx.x;
        float v[16];
#pragma unroll
        for (int i = 0; i < 16; i++) v[i] = M[bh * LL + i * 64 + lane];

        for (int k = 0; k < UU; k++) {
            float bv = -INFINITY; int bi = 0x7fffffff;
#pragma unroll
            for (int i = 0; i < 16; i++) {
                if (v[i] > bv) { bv = v[i]; bi = i * 64 + lane; }
            }
#pragma unroll
            for (int w = 1; w < 64; w <<= 1) {
                float ov = __shfl_xor(bv, w);
                int   oi = __shfl_xor(bi, w);
                if (ov > bv || (ov == bv && oi < bi)) { bv = ov; bi = oi; }
            }
            if (lane == 0) top[bh * UU + k] = bi;
            if ((bi & 63) == lane) {
                int slot = bi >> 6;
#pragma unroll
                for (int i = 0; i < 16; i++) if (i == slot) v[i] = -INFINITY;
            }
        }
    } else {
        // ---- csum2: scan within chunk, write context ----
        int blk = blockIdx.x - BH;
        int bh = blk >> 5, c = blk & (CH - 1);
        int b = bh >> 3, h = bh & 7;
        int d = threadIdx.x;
        float prefix = 0.f;
#pragma unroll
        for (int cc = 0; cc < CH; cc++) {
            float vv = csum[(size_t)(bh * CH + cc) * 64 + d];
            prefix += (cc < c) ? vv : 0.f;
        }
        int l0 = c * CROWS;
        const float* vp = V + qkv_off(b, l0, h, d);
        float* op = out + qkv_off(b, l0, h, d);
        float run = prefix;
#pragma unroll
        for (int i = 0; i < CROWS; i++) {
            run += vp[(size_t)i * (HH * DD)];
            op[(size_t)i * (HH * DD)] = run / (float)(l0 + i + 1);
        }
    }
}

// ---------------- Stage 4a: MFMA flash-attention partials per (bh, chunk) ----------------
__global__ __launch_bounds__(256) void kernel_attn_part(const float* __restrict__ Q,
                                                        const float* __restrict__ K,
                                                        const float* __restrict__ V,
                                                        const int*   __restrict__ top,
                                                        float* __restrict__ m_ws,
                                                        float* __restrict__ se_ws,
                                                        float* __restrict__ pv_ws) {
    __shared__ unsigned short vt[64 * CHK];      // V^T, 16B-slot swizzled
    __shared__ unsigned short p_lds[RPAD * CHK]; // P (exp'd scores), bf16
    __shared__ float red_m[4][RPAD];
    __shared__ float red_se[4][RPAD];
    __shared__ int   qpos_s[RPAD];

    const int blk = blockIdx.x;          // bh*NCHK + ch
    const int bh  = blk >> 2;
    const int ch  = blk & 3;
    const int b   = bh >> 3, h = bh & 7;
    const int l0  = ch * CHK;
    const int tid = threadIdx.x;
    const int w    = tid >> 6;
    const int lane = tid & 63;
    const int c    = lane & 15;
    const int g    = lane >> 4;
    const float scale = 0.125f;

    if (tid < RPAD) qpos_s[tid] = top[bh * UU + (tid < UU ? tid : UU - 1)];

#pragma unroll
    for (int i = 0; i < 8; i++) {
        int task = i * 256 + tid;
        int d   = task & 63;
        int lq8 = task >> 6;
        float vv[8];
#pragma unroll
        for (int j = 0; j < 8; j++)
            vv[j] = V[qkv_off(b, l0 + lq8 * 8 + j, h, d)];
        short8 pk;
#pragma unroll
        for (int j = 0; j < 8; j++) pk[j] = (short)f2bf(vv[j]);
        *reinterpret_cast<short8*>(vt + d * CHK + (((lq8 ^ (d & 31)) << 3))) = pk;
    }
    __syncthreads();

    f32x4 acc[3][4];
#pragma unroll
    for (int mt = 0; mt < 3; mt++)
#pragma unroll
        for (int nt = 0; nt < 4; nt++) acc[mt][nt] = (f32x4){0.f, 0.f, 0.f, 0.f};

#pragma unroll
    for (int ks = 0; ks < 2; ks++) {
        int k0 = ks * 32 + g * 8;
        short8 af[3];
#pragma unroll
        for (int mt = 0; mt < 3; mt++) {
            int row = mt * 16 + c;
            af[mt] = ld_bf8_g(Q + qkv_off(b, qpos_s[row], h, k0));
        }
#pragma unroll
        for (int nt = 0; nt < 4; nt++) {
            int kl = l0 + w * 64 + nt * 16 + c;
            short8 bf = ld_bf8_g(K + qkv_off(b, kl, h, k0));
#pragma unroll
            for (int mt = 0; mt < 3; mt++)
                acc[mt][nt] = __builtin_amdgcn_mfma_f32_16x16x32_bf16(af[mt], bf, acc[mt][nt], 0, 0, 0);
        }
    }

    float tmax[3][4];
#pragma unroll
    for (int mt = 0; mt < 3; mt++)
#pragma unroll
        for (int r = 0; r < 4; r++) {
            float m = fmaxf(fmaxf(acc[mt][0][r], acc[mt][1][r]),
                            fmaxf(acc[mt][2][r], acc[mt][3][r]));
            m = fmaxf(m, __shfl_xor(m, 1));
            m = fmaxf(m, __shfl_xor(m, 2));
            m = fmaxf(m, __shfl_xor(m, 4));
            m = fmaxf(m, __shfl_xor(m, 8));
            tmax[mt][r] = m;
        }
    if (c == 0) {
#pragma unroll
        for (int mt = 0; mt < 3; mt++)
#pragma unroll
            for (int r = 0; r < 4; r++)
                red_m[w][mt * 16 + g * 4 + r] = tmax[mt][r];
    }
    __syncthreads();

    float tse[3][4];
#pragma unroll
    for (int mt = 0; mt < 3; mt++)
#pragma unroll
        for (int r = 0; r < 4; r++) {
            int row = mt * 16 + g * 4 + r;
            float m = fmaxf(fmaxf(red_m[0][row], red_m[1][row]),
                            fmaxf(red_m[2][row], red_m[3][row]));
            float s = 0.f;
#pragma unroll
            for (int nt = 0; nt < 4; nt++) {
                float p = __expf(scale * (acc[mt][nt][r] - m));
                acc[mt][nt][r] = p;
                s += p;
                p_lds[row * CHK + w * 64 + nt * 16 + c] = f2bf(p);
            }
            s += __shfl_xor(s, 1);
            s += __shfl_xor(s, 2);
            s += __shfl_xor(s, 4);
            s += __shfl_xor(s, 8);
            tse[mt][r] = s;
        }
    if (c == 0) {
#pragma unroll
        for (int mt = 0; mt < 3; mt++)
#pragma unroll
            for (int r = 0; r < 4; r++)
                red_se[w][mt * 16 + g * 4 + r] = tse[mt][r];
    }
    __syncthreads();

    if (tid < RPAD) {
        float mm = fmaxf(fmaxf(red_m[0][tid], red_m[1][tid]),
                         fmaxf(red_m[2][tid], red_m[3][tid]));
        float ss = red_se[0][tid] + red_se[1][tid] + red_se[2][tid] + red_se[3][tid];
        m_ws[blk * RPAD + tid]  = mm;
        se_ws[blk * RPAD + tid] = ss;
    }

    f32x4 acc2[3];
#pragma unroll
    for (int mt = 0; mt < 3; mt++) acc2[mt] = (f32x4){0.f, 0.f, 0.f, 0.f};

#pragma unroll
    for (int ks = 0; ks < 8; ks++) {
        int slot = ks * 4 + g;
        int d    = w * 16 + c;
        short8 bf = *reinterpret_cast<const short8*>(
            vt + d * CHK + ((slot ^ (d & 31)) << 3));
#pragma unroll
        for (int mt = 0; mt < 3; mt++) {
            short8 af = *reinterpret_cast<const short8*>(
                p_lds + (mt * 16 + c) * CHK + ks * 32 + g * 8);
            acc2[mt] = __builtin_amdgcn_mfma_f32_16x16x32_bf16(af, bf, acc2[mt], 0, 0, 0);
        }
    }

#pragma unroll
    for (int mt = 0; mt < 3; mt++)
#pragma unroll
        for (int r = 0; r < 4; r++) {
            int row = mt * 16 + g * 4 + r;
            pv_ws[((size_t)blk * RPAD + row) * 64 + w * 16 + c] = acc2[mt][r];
        }
}

// ---------------- Stage 4b: combine chunk partials, write selected rows ----------------
__global__ __launch_bounds__(256) void kernel_attn_comb(const int* __restrict__ top,
                                                        const float* __restrict__ m_ws,
                                                        const float* __restrict__ se_ws,
                                                        const float* __restrict__ pv_ws,
                                                        float* __restrict__ out) {
    int bh = blockIdx.x;
    int b = bh >> 3, h = bh & 7;
    const float scale = 0.125f;
    for (int idx = threadIdx.x; idx < UU * 64; idx += 256) {
        int r = idx >> 6, d = idx & 63;
        float mc[NCHK];
        float mm = -INFINITY;
#pragma unroll
        for (int ch = 0; ch < NCHK; ch++) {
            mc[ch] = m_ws[(bh * NCHK + ch) * RPAD + r];
            mm = fmaxf(mm, mc[ch]);
        }
        float num = 0.f, den = 0.f;
#pragma unroll
        for (int ch = 0; ch < NCHK; ch++) {
            float f = __expf(scale * (mc[ch] - mm));
            num += f * pv_ws[((size_t)(bh * NCHK + ch) * RPAD + r) * 64 + d];
            den += f * se_ws[(bh * NCHK + ch) * RPAD + r];
        }
        out[qkv_off(b, top[bh * UU + r], h, d)] = num / den;
    }
}

extern "C" void kernel_launch(void* const* d_in, const int* in_sizes, int n_in,
                              void* d_out, int out_size, void* d_ws, size_t ws_size,
                              hipStream_t stream) {
    const float* Q    = (const float*)d_in[0];
    const float* K    = (const float*)d_in[1];
    const float* V    = (const float*)d_in[2];
    const int*   sidx = (const int*)d_in[3];
    float* out = (float*)d_out;

    char* ws = (char*)d_ws;
    float* M     = (float*)(ws);                          // 256 KiB
    int*   top   = (int*)  (ws + 262144);                 // 9 KiB
    float* csum  = (float*)(ws + 271360);                 // 512 KiB
    float* m_ws  = (float*)(ws + 795648);                 // 48 KiB
    float* se_ws = (float*)(ws + 844800);                 // 48 KiB
    float* pv_ws = (float*)(ws + 893952);                 // 3 MiB

    kernel_M_csum1  <<<MBLOCKS + C1BLOCKS, 256, 0, stream>>>(Q, K, V, sidx, M, csum);
    kernel_topk_csum2<<<BH + C1BLOCKS, 64, 0, stream>>>(M, top, V, csum, out);
    kernel_attn_part<<<BH * NCHK, 256, 0, stream>>>(Q, K, V, top, m_ws, se_ws, pv_ws);
    kernel_attn_comb<<<BH, 256, 0, stream>>>(top, m_ws, se_ws, pv_ws, out);
}

// Round 5
// 81.659 us; speedup vs baseline: 2.7675x; 1.0234x over previous
//
#include <hip/hip_runtime.h>
#include <math.h>

#define BB 8
#define LL 1024
#define HH 8
#define DD 64
#define SS 35
#define UU 35
#define BH (BB*HH)
#define CH 32            // cumsum chunks per (b,h)
#define CROWS (LL/CH)    // 32 rows per chunk
#define NCHK 4           // attention K/V chunks
#define CHK 256          // keys per chunk
#define RPAD 48          // padded row count (35 -> 48, 3 m-tiles)

#define MBLOCKS 16384    // kernel_M waves/4
#define C1BLOCKS (BH*CH) // 2048

typedef __attribute__((ext_vector_type(8))) short short8;
typedef __attribute__((ext_vector_type(4))) float f32x4;

__device__ __forceinline__ size_t qkv_off(int b, int l, int h, int d) {
    return (((size_t)b*LL + l)*HH + h)*DD + d;
}

__device__ __forceinline__ unsigned short f2bf(float x) {
    unsigned int u = __float_as_uint(x);
    u = (u + 0x7fffu + ((u >> 16) & 1u)) >> 16;
    return (unsigned short)u;
}

__device__ __forceinline__ short8 ld_bf8_g(const float* __restrict__ p) {
    float4 x = *reinterpret_cast<const float4*>(p);
    float4 y = *reinterpret_cast<const float4*>(p + 4);
    short8 r;
    r[0] = (short)f2bf(x.x); r[1] = (short)f2bf(x.y);
    r[2] = (short)f2bf(x.z); r[3] = (short)f2bf(x.w);
    r[4] = (short)f2bf(y.x); r[5] = (short)f2bf(y.y);
    r[6] = (short)f2bf(y.z); r[7] = (short)f2bf(y.w);
    return r;
}

// ---------------- L1: kernel_M (XCD-swizzled, MLP-forced) + csum1 fused ----------------
__global__ __launch_bounds__(256, 4) void kernel_M_csum1(const float* __restrict__ Q,
                                                         const float* __restrict__ K,
                                                         const float* __restrict__ V,
                                                         const int*   __restrict__ sidx,
                                                         float* __restrict__ M,
                                                         float* __restrict__ csum) {
    int blk = blockIdx.x;
    if (blk < MBLOCKS) {
        // ---- sparsity measurement M: one wave per q ----
        int xcd  = blk & 7;
        int slot = blk >> 3;
        int bh   = ((slot >> 8) << 3) | xcd;   // bh%8 == xcd -> per-XCD K locality
        int j    = slot & 255;
        int widx = threadIdx.x >> 6, lane = threadIdx.x & 63;
        int q = j * 4 + widx;
        int b = bh >> 3, h = bh & 7;
        int sub = lane & 15, grp = lane >> 4;

        const f32x4 q4 = *reinterpret_cast<const f32x4*>(Q + qkv_off(b, q, h, sub * 4));
        const int* si = sidx + q * SS;

        // batch all 9 index loads in flight
        int idxv[9];
#pragma unroll
        for (int i = 0; i < 9; i++) {
            int s = i * 4 + grp;
            idxv[i] = si[s < SS ? s : 0];
        }
        asm volatile("" : "+v"(idxv[0]), "+v"(idxv[1]), "+v"(idxv[2]),
                          "+v"(idxv[3]), "+v"(idxv[4]), "+v"(idxv[5]),
                          "+v"(idxv[6]), "+v"(idxv[7]), "+v"(idxv[8]));

        // batch all 9 K-row gathers in flight (36 VGPRs live, forced)
        f32x4 kv[9];
#pragma unroll
        for (int i = 0; i < 9; i++)
            kv[i] = *reinterpret_cast<const f32x4*>(K + qkv_off(b, idxv[i], h, sub * 4));
        asm volatile("" : "+v"(kv[0]), "+v"(kv[1]), "+v"(kv[2]),
                          "+v"(kv[3]), "+v"(kv[4]), "+v"(kv[5]),
                          "+v"(kv[6]), "+v"(kv[7]), "+v"(kv[8]));

        float mx = -INFINITY, sm = 0.f;
#pragma unroll
        for (int i = 0; i < 9; i++) {
            float p = q4.x * kv[i].x + q4.y * kv[i].y + q4.z * kv[i].z + q4.w * kv[i].w;
            p += __shfl_xor(p, 1);
            p += __shfl_xor(p, 2);
            p += __shfl_xor(p, 4);
            p += __shfl_xor(p, 8);
            if (i * 4 + grp < SS) { mx = fmaxf(mx, p); sm += p; }
        }
        mx = fmaxf(mx, __shfl_xor(mx, 16)); sm += __shfl_xor(sm, 16);
        mx = fmaxf(mx, __shfl_xor(mx, 32)); sm += __shfl_xor(sm, 32);
        if (lane == 0) M[bh * LL + q] = mx - sm * (1.0f / LL);
    } else {
        // ---- csum1: per-chunk column sums ----
        int blk2 = blk - MBLOCKS;
        int bh = blk2 >> 5, c = blk2 & (CH - 1);
        int b = bh >> 3, h = bh & 7;
        int d = threadIdx.x & 63, seg = threadIdx.x >> 6;
        int l0 = c * CROWS + seg * (CROWS / 4);
        const float* vp = V + qkv_off(b, l0, h, d);
        float vr[CROWS / 4];
#pragma unroll
        for (int i = 0; i < CROWS / 4; i++) vr[i] = vp[(size_t)i * (HH * DD)];
        float s = 0.f;
#pragma unroll
        for (int i = 0; i < CROWS / 4; i++) s += vr[i];
        __shared__ float red[4][64];
        red[seg][d] = s;
        __syncthreads();
        if (seg == 0)
            csum[(size_t)blk2 * 64 + d] = red[0][d] + red[1][d] + red[2][d] + red[3][d];
    }
}

// ---------------- L2: topk + csum2 fused (64-thread blocks) ----------------
__global__ __launch_bounds__(64, 4) void kernel_topk_csum2(const float* __restrict__ M,
                                                           int* __restrict__ top,
                                                           const float* __restrict__ V,
                                                           const float* __restrict__ csum,
                                                           float* __restrict__ out) {
    if (blockIdx.x < BH) {
        // ---- top-U per (b,h), single wave, shfl-only ----
        int bh = blockIdx.x, lane = threadIdx.x;
        float v[16];
#pragma unroll
        for (int i = 0; i < 16; i++) v[i] = M[bh * LL + i * 64 + lane];

        for (int k = 0; k < UU; k++) {
            float bv = -INFINITY; int bi = 0x7fffffff;
#pragma unroll
            for (int i = 0; i < 16; i++) {
                if (v[i] > bv) { bv = v[i]; bi = i * 64 + lane; }
            }
#pragma unroll
            for (int w = 1; w < 64; w <<= 1) {
                float ov = __shfl_xor(bv, w);
                int   oi = __shfl_xor(bi, w);
                if (ov > bv || (ov == bv && oi < bi)) { bv = ov; bi = oi; }
            }
            if (lane == 0) top[bh * UU + k] = bi;
            if ((bi & 63) == lane) {
                int slot = bi >> 6;
#pragma unroll
                for (int i = 0; i < 16; i++) if (i == slot) v[i] = -INFINITY;
            }
        }
    } else {
        // ---- csum2: scan within chunk, write context ----
        int blk = blockIdx.x - BH;
        int bh = blk >> 5, c = blk & (CH - 1);
        int b = bh >> 3, h = bh & 7;
        int d = threadIdx.x;
        int l0 = c * CROWS;
        const float* vp = V + qkv_off(b, l0, h, d);

        // batch the 32 strided V loads in flight
        float vr[CROWS];
#pragma unroll
        for (int i = 0; i < CROWS; i++) vr[i] = vp[(size_t)i * (HH * DD)];

        float prefix = 0.f;
#pragma unroll
        for (int cc = 0; cc < CH; cc++) {
            float vv = csum[(size_t)(bh * CH + cc) * 64 + d];
            prefix += (cc < c) ? vv : 0.f;
        }
        float* op = out + qkv_off(b, l0, h, d);
        float run = prefix;
#pragma unroll
        for (int i = 0; i < CROWS; i++) {
            run += vr[i];
            op[(size_t)i * (HH * DD)] = run / (float)(l0 + i + 1);
        }
    }
}

// ---------------- Stage 4a: MFMA flash-attention partials per (bh, chunk) ----------------
__global__ __launch_bounds__(256) void kernel_attn_part(const float* __restrict__ Q,
                                                        const float* __restrict__ K,
                                                        const float* __restrict__ V,
                                                        const int*   __restrict__ top,
                                                        float* __restrict__ m_ws,
                                                        float* __restrict__ se_ws,
                                                        float* __restrict__ pv_ws) {
    __shared__ unsigned short vt[64 * CHK];      // V^T, 16B-slot swizzled
    __shared__ unsigned short p_lds[RPAD * CHK]; // P (exp'd scores), bf16
    __shared__ float red_m[4][RPAD];
    __shared__ float red_se[4][RPAD];
    __shared__ int   qpos_s[RPAD];

    const int blk = blockIdx.x;          // bh*NCHK + ch
    const int bh  = blk >> 2;
    const int ch  = blk & 3;
    const int b   = bh >> 3, h = bh & 7;
    const int l0  = ch * CHK;
    const int tid = threadIdx.x;
    const int w    = tid >> 6;
    const int lane = tid & 63;
    const int c    = lane & 15;
    const int g    = lane >> 4;
    const float scale = 0.125f;

    if (tid < RPAD) qpos_s[tid] = top[bh * UU + (tid < UU ? tid : UU - 1)];

#pragma unroll
    for (int i = 0; i < 8; i++) {
        int task = i * 256 + tid;
        int d   = task & 63;
        int lq8 = task >> 6;
        float vv[8];
#pragma unroll
        for (int j = 0; j < 8; j++)
            vv[j] = V[qkv_off(b, l0 + lq8 * 8 + j, h, d)];
        short8 pk;
#pragma unroll
        for (int j = 0; j < 8; j++) pk[j] = (short)f2bf(vv[j]);
        *reinterpret_cast<short8*>(vt + d * CHK + (((lq8 ^ (d & 31)) << 3))) = pk;
    }
    __syncthreads();

    f32x4 acc[3][4];
#pragma unroll
    for (int mt = 0; mt < 3; mt++)
#pragma unroll
        for (int nt = 0; nt < 4; nt++) acc[mt][nt] = (f32x4){0.f, 0.f, 0.f, 0.f};

#pragma unroll
    for (int ks = 0; ks < 2; ks++) {
        int k0 = ks * 32 + g * 8;
        short8 af[3];
#pragma unroll
        for (int mt = 0; mt < 3; mt++) {
            int row = mt * 16 + c;
            af[mt] = ld_bf8_g(Q + qkv_off(b, qpos_s[row], h, k0));
        }
#pragma unroll
        for (int nt = 0; nt < 4; nt++) {
            int kl = l0 + w * 64 + nt * 16 + c;
            short8 bf = ld_bf8_g(K + qkv_off(b, kl, h, k0));
#pragma unroll
            for (int mt = 0; mt < 3; mt++)
                acc[mt][nt] = __builtin_amdgcn_mfma_f32_16x16x32_bf16(af[mt], bf, acc[mt][nt], 0, 0, 0);
        }
    }

    float tmax[3][4];
#pragma unroll
    for (int mt = 0; mt < 3; mt++)
#pragma unroll
        for (int r = 0; r < 4; r++) {
            float m = fmaxf(fmaxf(acc[mt][0][r], acc[mt][1][r]),
                            fmaxf(acc[mt][2][r], acc[mt][3][r]));
            m = fmaxf(m, __shfl_xor(m, 1));
            m = fmaxf(m, __shfl_xor(m, 2));
            m = fmaxf(m, __shfl_xor(m, 4));
            m = fmaxf(m, __shfl_xor(m, 8));
            tmax[mt][r] = m;
        }
    if (c == 0) {
#pragma unroll
        for (int mt = 0; mt < 3; mt++)
#pragma unroll
            for (int r = 0; r < 4; r++)
                red_m[w][mt * 16 + g * 4 + r] = tmax[mt][r];
    }
    __syncthreads();

    float tse[3][4];
#pragma unroll
    for (int mt = 0; mt < 3; mt++)
#pragma unroll
        for (int r = 0; r < 4; r++) {
            int row = mt * 16 + g * 4 + r;
            float m = fmaxf(fmaxf(red_m[0][row], red_m[1][row]),
                            fmaxf(red_m[2][row], red_m[3][row]));
            float s = 0.f;
#pragma unroll
            for (int nt = 0; nt < 4; nt++) {
                float p = __expf(scale * (acc[mt][nt][r] - m));
                acc[mt][nt][r] = p;
                s += p;
                p_lds[row * CHK + w * 64 + nt * 16 + c] = f2bf(p);
            }
            s += __shfl_xor(s, 1);
            s += __shfl_xor(s, 2);
            s += __shfl_xor(s, 4);
            s += __shfl_xor(s, 8);
            tse[mt][r] = s;
        }
    if (c == 0) {
#pragma unroll
        for (int mt = 0; mt < 3; mt++)
#pragma unroll
            for (int r = 0; r < 4; r++)
                red_se[w][mt * 16 + g * 4 + r] = tse[mt][r];
    }
    __syncthreads();

    if (tid < RPAD) {
        float mm = fmaxf(fmaxf(red_m[0][tid], red_m[1][tid]),
                         fmaxf(red_m[2][tid], red_m[3][tid]));
        float ss = red_se[0][tid] + red_se[1][tid] + red_se[2][tid] + red_se[3][tid];
        m_ws[blk * RPAD + tid]  = mm;
        se_ws[blk * RPAD + tid] = ss;
    }

    f32x4 acc2[3];
#pragma unroll
    for (int mt = 0; mt < 3; mt++) acc2[mt] = (f32x4){0.f, 0.f, 0.f, 0.f};

#pragma unroll
    for (int ks = 0; ks < 8; ks++) {
        int slot = ks * 4 + g;
        int d    = w * 16 + c;
        short8 bf = *reinterpret_cast<const short8*>(
            vt + d * CHK + ((slot ^ (d & 31)) << 3));
#pragma unroll
        for (int mt = 0; mt < 3; mt++) {
            short8 af = *reinterpret_cast<const short8*>(
                p_lds + (mt * 16 + c) * CHK + ks * 32 + g * 8);
            acc2[mt] = __builtin_amdgcn_mfma_f32_16x16x32_bf16(af, bf, acc2[mt], 0, 0, 0);
        }
    }

#pragma unroll
    for (int mt = 0; mt < 3; mt++)
#pragma unroll
        for (int r = 0; r < 4; r++) {
            int row = mt * 16 + g * 4 + r;
            pv_ws[((size_t)blk * RPAD + row) * 64 + w * 16 + c] = acc2[mt][r];
        }
}

// ---------------- Stage 4b: combine chunk partials, write selected rows ----------------
__global__ __launch_bounds__(256) void kernel_attn_comb(const int* __restrict__ top,
                                                        const float* __restrict__ m_ws,
                                                        const float* __restrict__ se_ws,
                                                        const float* __restrict__ pv_ws,
                                                        float* __restrict__ out) {
    int bh = blockIdx.x;
    int b = bh >> 3, h = bh & 7;
    const float scale = 0.125f;
    for (int idx = threadIdx.x; idx < UU * 64; idx += 256) {
        int r = idx >> 6, d = idx & 63;
        float mc[NCHK];
        float mm = -INFINITY;
#pragma unroll
        for (int ch = 0; ch < NCHK; ch++) {
            mc[ch] = m_ws[(bh * NCHK + ch) * RPAD + r];
            mm = fmaxf(mm, mc[ch]);
        }
        float num = 0.f, den = 0.f;
#pragma unroll
        for (int ch = 0; ch < NCHK; ch++) {
            float f = __expf(scale * (mc[ch] - mm));
            num += f * pv_ws[((size_t)(bh * NCHK + ch) * RPAD + r) * 64 + d];
            den += f * se_ws[(bh * NCHK + ch) * RPAD + r];
        }
        out[qkv_off(b, top[bh * UU + r], h, d)] = num / den;
    }
}

extern "C" void kernel_launch(void* const* d_in, const int* in_sizes, int n_in,
                              void* d_out, int out_size, void* d_ws, size_t ws_size,
                              hipStream_t stream) {
    const float* Q    = (const float*)d_in[0];
    const float* K    = (const float*)d_in[1];
    const float* V    = (const float*)d_in[2];
    const int*   sidx = (const int*)d_in[3];
    float* out = (float*)d_out;

    char* ws = (char*)d_ws;
    float* M     = (float*)(ws);                          // 256 KiB
    int*   top   = (int*)  (ws + 262144);                 // 9 KiB
    float* csum  = (float*)(ws + 271360);                 // 512 KiB
    float* m_ws  = (float*)(ws + 795648);                 // 48 KiB
    float* se_ws = (float*)(ws + 844800);                 // 48 KiB
    float* pv_ws = (float*)(ws + 893952);                 // 3 MiB

    kernel_M_csum1  <<<MBLOCKS + C1BLOCKS, 256, 0, stream>>>(Q, K, V, sidx, M, csum);
    kernel_topk_csum2<<<BH + C1BLOCKS, 64, 0, stream>>>(M, top, V, csum, out);
    kernel_attn_part<<<BH * NCHK, 256, 0, stream>>>(Q, K, V, top, m_ws, se_ws, pv_ws);
    kernel_attn_comb<<<BH, 256, 0, stream>>>(top, m_ws, se_ws, pv_ws, out);
}

// Round 6
// 80.439 us; speedup vs baseline: 2.8095x; 1.0152x over previous
//
#include <hip/hip_runtime.h>
#include <math.h>

#define BB 8
#define LL 1024
#define HH 8
#define DD 64
#define SS 35
#define UU 35
#define BH (BB*HH)
#define CH 32            // cumsum chunks per (b,h)
#define CROWS (LL/CH)    // 32 rows per chunk
#define NCHK 4           // attention K/V chunks
#define CHK 256          // keys per chunk
#define RPAD 48          // padded row count (35 -> 48, 3 m-tiles)

#define MBLOCKS2 8192    // kernel_M blocks: 2 q per wave, 4 waves/block
#define C1BLOCKS (BH*CH) // 2048

typedef __attribute__((ext_vector_type(8))) short short8;
typedef __attribute__((ext_vector_type(4))) float f32x4;

__device__ __forceinline__ size_t qkv_off(int b, int l, int h, int d) {
    return (((size_t)b*LL + l)*HH + h)*DD + d;
}

__device__ __forceinline__ unsigned short f2bf(float x) {
    unsigned int u = __float_as_uint(x);
    u = (u + 0x7fffu + ((u >> 16) & 1u)) >> 16;
    return (unsigned short)u;
}

__device__ __forceinline__ short8 ld_bf8_g(const float* __restrict__ p) {
    float4 x = *reinterpret_cast<const float4*>(p);
    float4 y = *reinterpret_cast<const float4*>(p + 4);
    short8 r;
    r[0] = (short)f2bf(x.x); r[1] = (short)f2bf(x.y);
    r[2] = (short)f2bf(x.z); r[3] = (short)f2bf(x.w);
    r[4] = (short)f2bf(y.x); r[5] = (short)f2bf(y.y);
    r[6] = (short)f2bf(y.z); r[7] = (short)f2bf(y.w);
    return r;
}

// sum over a 16-lane DPP row (lanes are contiguous within the row) — VALU-only
__device__ __forceinline__ float row16_sum(float p) {
    int t;
    t = __builtin_amdgcn_update_dpp(0, __float_as_int(p), 0xB1, 0xF, 0xF, true);  // quad_perm [1,0,3,2]
    p += __int_as_float(t);
    t = __builtin_amdgcn_update_dpp(0, __float_as_int(p), 0x4E, 0xF, 0xF, true);  // quad_perm [2,3,0,1]
    p += __int_as_float(t);
    t = __builtin_amdgcn_update_dpp(0, __float_as_int(p), 0x141, 0xF, 0xF, true); // row_half_mirror
    p += __int_as_float(t);
    t = __builtin_amdgcn_update_dpp(0, __float_as_int(p), 0x140, 0xF, 0xF, true); // row_mirror
    p += __int_as_float(t);
    return p;
}

// ---------------- L1: kernel_M (2q/wave, DPP reduce, XCD-swizzled) + csum1 fused ----------------
__global__ __launch_bounds__(256, 3) void kernel_M_csum1(const float* __restrict__ Q,
                                                         const float* __restrict__ K,
                                                         const float* __restrict__ V,
                                                         const int*   __restrict__ sidx,
                                                         float* __restrict__ M,
                                                         float* __restrict__ csum) {
    int blk = blockIdx.x;
    if (blk < MBLOCKS2) {
        // ---- sparsity measurement M: one wave per 2 queries ----
        int xcd  = blk & 7;
        int slot = blk >> 3;                 // 0..1023
        int bh   = ((slot >> 7) << 3) | xcd; // bh%8 == xcd -> per-XCD K locality
        int j    = slot & 127;
        int widx = threadIdx.x >> 6, lane = threadIdx.x & 63;
        int q0   = j * 8 + widx * 2;
        int b = bh >> 3, h = bh & 7;
        int sub = lane & 15, g = lane >> 4;

        int base = (((b << 13) + h) << 6) + (sub << 2);  // elem offset of (b,0,h,sub*4)
        const f32x4 qa = *reinterpret_cast<const f32x4*>(Q + base + (q0 << 9));
        const f32x4 qb = *reinterpret_cast<const f32x4*>(Q + base + ((q0 + 1) << 9));

        // grp g owns samples 9g..9g+8 (g=3: 9*3+8==35 invalid -> dup slot 7, masked)
        const int* sia = sidx + q0 * SS + g * 9;
        const int* sib = sia + SS;

        int ia[9], ib[9];
#pragma unroll
        for (int i = 0; i < 9; i++) {
            int ii = (i == 8 && g == 3) ? 7 : i;   // OOB clamp (also avoids sidx overrun)
            ia[i] = sia[ii];
            ib[i] = sib[ii];
        }

        f32x4 ka[9], kb[9];
#pragma unroll
        for (int i = 0; i < 9; i++)
            ka[i] = *reinterpret_cast<const f32x4*>(K + base + ((unsigned)ia[i] << 9));
#pragma unroll
        for (int i = 0; i < 9; i++)
            kb[i] = *reinterpret_cast<const f32x4*>(K + base + ((unsigned)ib[i] << 9));

        float mxa = 0.f, sma = 0.f, mxb = 0.f, smb = 0.f;
#pragma unroll
        for (int i = 0; i < 9; i++) {
            float p = qa.x * ka[i].x + qa.y * ka[i].y + qa.z * ka[i].z + qa.w * ka[i].w;
            p = row16_sum(p);
            if (i == 0)      { mxa = p; sma = p; }
            else if (i < 8)  { mxa = fmaxf(mxa, p); sma += p; }
            else             { bool v = (g < 3);
                               mxa = fmaxf(mxa, v ? p : -INFINITY);
                               sma += v ? p : 0.f; }
        }
#pragma unroll
        for (int i = 0; i < 9; i++) {
            float p = qb.x * kb[i].x + qb.y * kb[i].y + qb.z * kb[i].z + qb.w * kb[i].w;
            p = row16_sum(p);
            if (i == 0)      { mxb = p; smb = p; }
            else if (i < 8)  { mxb = fmaxf(mxb, p); smb += p; }
            else             { bool v = (g < 3);
                               mxb = fmaxf(mxb, v ? p : -INFINITY);
                               smb += v ? p : 0.f; }
        }

        // cross-grp (row) combine
        mxa = fmaxf(mxa, __shfl_xor(mxa, 16)); sma += __shfl_xor(sma, 16);
        mxa = fmaxf(mxa, __shfl_xor(mxa, 32)); sma += __shfl_xor(sma, 32);
        mxb = fmaxf(mxb, __shfl_xor(mxb, 16)); smb += __shfl_xor(smb, 16);
        mxb = fmaxf(mxb, __shfl_xor(mxb, 32)); smb += __shfl_xor(smb, 32);

        if (lane == 0) {
            M[bh * LL + q0]     = mxa - sma * (1.0f / LL);
            M[bh * LL + q0 + 1] = mxb - smb * (1.0f / LL);
        }
    } else {
        // ---- csum1: per-chunk column sums ----
        int blk2 = blk - MBLOCKS2;
        int bh = blk2 >> 5, c = blk2 & (CH - 1);
        int b = bh >> 3, h = bh & 7;
        int d = threadIdx.x & 63, seg = threadIdx.x >> 6;
        int l0 = c * CROWS + seg * (CROWS / 4);
        const float* vp = V + qkv_off(b, l0, h, d);
        float vr[CROWS / 4];
#pragma unroll
        for (int i = 0; i < CROWS / 4; i++) vr[i] = vp[(size_t)i * (HH * DD)];
        float s = 0.f;
#pragma unroll
        for (int i = 0; i < CROWS / 4; i++) s += vr[i];
        __shared__ float red[4][64];
        red[seg][d] = s;
        __syncthreads();
        if (seg == 0)
            csum[(size_t)blk2 * 64 + d] = red[0][d] + red[1][d] + red[2][d] + red[3][d];
    }
}

// ---------------- L2: topk + csum2 fused (64-thread blocks) ----------------
__global__ __launch_bounds__(64, 4) void kernel_topk_csum2(const float* __restrict__ M,
                                                           int* __restrict__ top,
                                                           const float* __restrict__ V,
                                                           const float* __restrict__ csum,
                                                           float* __restrict__ out) {
    if (blockIdx.x < BH) {
        // ---- top-U per (b,h), single wave, shfl-only ----
        int bh = blockIdx.x, lane = threadIdx.x;
        float v[16];
#pragma unroll
        for (int i = 0; i < 16; i++) v[i] = M[bh * LL + i * 64 + lane];

        for (int k = 0; k < UU; k++) {
            float bv = -INFINITY; int bi = 0x7fffffff;
#pragma unroll
            for (int i = 0; i < 16; i++) {
                if (v[i] > bv) { bv = v[i]; bi = i * 64 + lane; }
            }
#pragma unroll
            for (int w = 1; w < 64; w <<= 1) {
                float ov = __shfl_xor(bv, w);
                int   oi = __shfl_xor(bi, w);
                if (ov > bv || (ov == bv && oi < bi)) { bv = ov; bi = oi; }
            }
            if (lane == 0) top[bh * UU + k] = bi;
            if ((bi & 63) == lane) {
                int slot = bi >> 6;
#pragma unroll
                for (int i = 0; i < 16; i++) if (i == slot) v[i] = -INFINITY;
            }
        }
    } else {
        // ---- csum2: scan within chunk, write context ----
        int blk = blockIdx.x - BH;
        int bh = blk >> 5, c = blk & (CH - 1);
        int b = bh >> 3, h = bh & 7;
        int d = threadIdx.x;
        int l0 = c * CROWS;
        const float* vp = V + qkv_off(b, l0, h, d);

        float vr[CROWS];
#pragma unroll
        for (int i = 0; i < CROWS; i++) vr[i] = vp[(size_t)i * (HH * DD)];

        float prefix = 0.f;
#pragma unroll
        for (int cc = 0; cc < CH; cc++) {
            float vv = csum[(size_t)(bh * CH + cc) * 64 + d];
            prefix += (cc < c) ? vv : 0.f;
        }
        float* op = out + qkv_off(b, l0, h, d);
        float run = prefix;
#pragma unroll
        for (int i = 0; i < CROWS; i++) {
            run += vr[i];
            op[(size_t)i * (HH * DD)] = run / (float)(l0 + i + 1);
        }
    }
}

// ---------------- Stage 4a: MFMA flash-attention partials per (bh, chunk) ----------------
__global__ __launch_bounds__(256) void kernel_attn_part(const float* __restrict__ Q,
                                                        const float* __restrict__ K,
                                                        const float* __restrict__ V,
                                                        const int*   __restrict__ top,
                                                        float* __restrict__ m_ws,
                                                        float* __restrict__ se_ws,
                                                        float* __restrict__ pv_ws) {
    __shared__ unsigned short vt[64 * CHK];      // V^T, 16B-slot swizzled
    __shared__ unsigned short p_lds[RPAD * CHK]; // P (exp'd scores), bf16
    __shared__ float red_m[4][RPAD];
    __shared__ float red_se[4][RPAD];
    __shared__ int   qpos_s[RPAD];

    const int blk = blockIdx.x;          // bh*NCHK + ch
    const int bh  = blk >> 2;
    const int ch  = blk & 3;
    const int b   = bh >> 3, h = bh & 7;
    const int l0  = ch * CHK;
    const int tid = threadIdx.x;
    const int w    = tid >> 6;
    const int lane = tid & 63;
    const int c    = lane & 15;
    const int g    = lane >> 4;
    const float scale = 0.125f;

    if (tid < RPAD) qpos_s[tid] = top[bh * UU + (tid < UU ? tid : UU - 1)];

#pragma unroll
    for (int i = 0; i < 8; i++) {
        int task = i * 256 + tid;
        int d   = task & 63;
        int lq8 = task >> 6;
        float vv[8];
#pragma unroll
        for (int j = 0; j < 8; j++)
            vv[j] = V[qkv_off(b, l0 + lq8 * 8 + j, h, d)];
        short8 pk;
#pragma unroll
        for (int j = 0; j < 8; j++) pk[j] = (short)f2bf(vv[j]);
        *reinterpret_cast<short8*>(vt + d * CHK + (((lq8 ^ (d & 31)) << 3))) = pk;
    }
    __syncthreads();

    f32x4 acc[3][4];
#pragma unroll
    for (int mt = 0; mt < 3; mt++)
#pragma unroll
        for (int nt = 0; nt < 4; nt++) acc[mt][nt] = (f32x4){0.f, 0.f, 0.f, 0.f};

#pragma unroll
    for (int ks = 0; ks < 2; ks++) {
        int k0 = ks * 32 + g * 8;
        short8 af[3];
#pragma unroll
        for (int mt = 0; mt < 3; mt++) {
            int row = mt * 16 + c;
            af[mt] = ld_bf8_g(Q + qkv_off(b, qpos_s[row], h, k0));
        }
#pragma unroll
        for (int nt = 0; nt < 4; nt++) {
            int kl = l0 + w * 64 + nt * 16 + c;
            short8 bf = ld_bf8_g(K + qkv_off(b, kl, h, k0));
#pragma unroll
            for (int mt = 0; mt < 3; mt++)
                acc[mt][nt] = __builtin_amdgcn_mfma_f32_16x16x32_bf16(af[mt], bf, acc[mt][nt], 0, 0, 0);
        }
    }

    float tmax[3][4];
#pragma unroll
    for (int mt = 0; mt < 3; mt++)
#pragma unroll
        for (int r = 0; r < 4; r++) {
            float m = fmaxf(fmaxf(acc[mt][0][r], acc[mt][1][r]),
                            fmaxf(acc[mt][2][r], acc[mt][3][r]));
            m = fmaxf(m, __shfl_xor(m, 1));
            m = fmaxf(m, __shfl_xor(m, 2));
            m = fmaxf(m, __shfl_xor(m, 4));
            m = fmaxf(m, __shfl_xor(m, 8));
            tmax[mt][r] = m;
        }
    if (c == 0) {
#pragma unroll
        for (int mt = 0; mt < 3; mt++)
#pragma unroll
            for (int r = 0; r < 4; r++)
                red_m[w][mt * 16 + g * 4 + r] = tmax[mt][r];
    }
    __syncthreads();

    float tse[3][4];
#pragma unroll
    for (int mt = 0; mt < 3; mt++)
#pragma unroll
        for (int r = 0; r < 4; r++) {
            int row = mt * 16 + g * 4 + r;
            float m = fmaxf(fmaxf(red_m[0][row], red_m[1][row]),
                            fmaxf(red_m[2][row], red_m[3][row]));
            float s = 0.f;
#pragma unroll
            for (int nt = 0; nt < 4; nt++) {
                float p = __expf(scale * (acc[mt][nt][r] - m));
                acc[mt][nt][r] = p;
                s += p;
                p_lds[row * CHK + w * 64 + nt * 16 + c] = f2bf(p);
            }
            s += __shfl_xor(s, 1);
            s += __shfl_xor(s, 2);
            s += __shfl_xor(s, 4);
            s += __shfl_xor(s, 8);
            tse[mt][r] = s;
        }
    if (c == 0) {
#pragma unroll
        for (int mt = 0; mt < 3; mt++)
#pragma unroll
            for (int r = 0; r < 4; r++)
                red_se[w][mt * 16 + g * 4 + r] = tse[mt][r];
    }
    __syncthreads();

    if (tid < RPAD) {
        float mm = fmaxf(fmaxf(red_m[0][tid], red_m[1][tid]),
                         fmaxf(red_m[2][tid], red_m[3][tid]));
        float ss = red_se[0][tid] + red_se[1][tid] + red_se[2][tid] + red_se[3][tid];
        m_ws[blk * RPAD + tid]  = mm;
        se_ws[blk * RPAD + tid] = ss;
    }

    f32x4 acc2[3];
#pragma unroll
    for (int mt = 0; mt < 3; mt++) acc2[mt] = (f32x4){0.f, 0.f, 0.f, 0.f};

#pragma unroll
    for (int ks = 0; ks < 8; ks++) {
        int slot = ks * 4 + g;
        int d    = w * 16 + c;
        short8 bf = *reinterpret_cast<const short8*>(
            vt + d * CHK + ((slot ^ (d & 31)) << 3));
#pragma unroll
        for (int mt = 0; mt < 3; mt++) {
            short8 af = *reinterpret_cast<const short8*>(
                p_lds + (mt * 16 + c) * CHK + ks * 32 + g * 8);
            acc2[mt] = __builtin_amdgcn_mfma_f32_16x16x32_bf16(af, bf, acc2[mt], 0, 0, 0);
        }
    }

#pragma unroll
    for (int mt = 0; mt < 3; mt++)
#pragma unroll
        for (int r = 0; r < 4; r++) {
            int row = mt * 16 + g * 4 + r;
            pv_ws[((size_t)blk * RPAD + row) * 64 + w * 16 + c] = acc2[mt][r];
        }
}

// ---------------- Stage 4b: combine chunk partials, write selected rows ----------------
__global__ __launch_bounds__(256) void kernel_attn_comb(const int* __restrict__ top,
                                                        const float* __restrict__ m_ws,
                                                        const float* __restrict__ se_ws,
                                                        const float* __restrict__ pv_ws,
                                                        float* __restrict__ out) {
    int bh = blockIdx.x;
    int b = bh >> 3, h = bh & 7;
    const float scale = 0.125f;
    for (int idx = threadIdx.x; idx < UU * 64; idx += 256) {
        int r = idx >> 6, d = idx & 63;
        float mc[NCHK];
        float mm = -INFINITY;
#pragma unroll
        for (int ch = 0; ch < NCHK; ch++) {
            mc[ch] = m_ws[(bh * NCHK + ch) * RPAD + r];
            mm = fmaxf(mm, mc[ch]);
        }
        float num = 0.f, den = 0.f;
#pragma unroll
        for (int ch = 0; ch < NCHK; ch++) {
            float f = __expf(scale * (mc[ch] - mm));
            num += f * pv_ws[((size_t)(bh * NCHK + ch) * RPAD + r) * 64 + d];
            den += f * se_ws[(bh * NCHK + ch) * RPAD + r];
        }
        out[qkv_off(b, top[bh * UU + r], h, d)] = num / den;
    }
}

extern "C" void kernel_launch(void* const* d_in, const int* in_sizes, int n_in,
                              void* d_out, int out_size, void* d_ws, size_t ws_size,
                              hipStream_t stream) {
    const float* Q    = (const float*)d_in[0];
    const float* K    = (const float*)d_in[1];
    const float* V    = (const float*)d_in[2];
    const int*   sidx = (const int*)d_in[3];
    float* out = (float*)d_out;

    char* ws = (char*)d_ws;
    float* M     = (float*)(ws);                          // 256 KiB
    int*   top   = (int*)  (ws + 262144);                 // 9 KiB
    float* csum  = (float*)(ws + 271360);                 // 512 KiB
    float* m_ws  = (float*)(ws + 795648);                 // 48 KiB
    float* se_ws = (float*)(ws + 844800);                 // 48 KiB
    float* pv_ws = (float*)(ws + 893952);                 // 3 MiB

    kernel_M_csum1   <<<MBLOCKS2 + C1BLOCKS, 256, 0, stream>>>(Q, K, V, sidx, M, csum);
    kernel_topk_csum2<<<BH + C1BLOCKS, 64, 0, stream>>>(M, top, V, csum, out);
    kernel_attn_part <<<BH * NCHK, 256, 0, stream>>>(Q, K, V, top, m_ws, se_ws, pv_ws);
    kernel_attn_comb <<<BH, 256, 0, stream>>>(top, m_ws, se_ws, pv_ws, out);
}